// Round 5
// baseline (168.542 us; speedup 1.0000x reference)
//
#include <hip/hip_runtime.h>
#include <cmath>

#define NCELL 3721          // 61*61
#define KCLS 10
#define DDIM 12288          // 64*64*3
#define WPAD 2052           // LDS plane stride in floats (2052*4 B = 16B-aligned)

// d_out layout (all float32), concatenated in reference return order
#define OUT_PROB 0
#define OUT_LAB  37210
#define OUT_BOX  74420
#define OUT_VALID 223300

// ---------------- Stage 1: patch GEMM (+bias) + softmax ----------------
// 256 blocks x 1024 threads (1 block/CU, LDS-bound). Block = 4 patch-rows x
// 4 patch-cols. Each thread handles 4 CONSECUTIVE d for 4 patches:
//   x: 4x global_load_dwordx4, 16B-aligned (all offsets are multiples of 4
//      floats), consecutive lanes -> consecutive 16B = perfectly coalesced.
//   W: 10x ds_read_b128 from transposed [k][d] LDS plane; lanes read
//      consecutive 16B chunks = conflict-free pattern.
// Per 160 FMAs: 4 global + 10 LDS + ~12 int ops (vs 14 loads/40 FMAs before:
// 3.5x fewer memory instructions — R2/R3 showed this issue rate, not BW, was
// the k1 bottleneck).
__global__ __launch_bounds__(1024) void k1_logits(
    const float* __restrict__ x, const float* __restrict__ W,
    const float* __restrict__ b, float* __restrict__ out)
{
    __shared__ float wlds[KCLS * WPAD];          // 82,080 B
    __shared__ float red[4][4][4][KCLS];         //  2,560 B

    const int tid  = threadIdx.x;
    const int tsub = tid & 255;          // d-lane within row group
    const int wrow = tid >> 8;           // patch-row within block (0..3)
    const int blk  = blockIdx.x;
    const int rg   = blk >> 4;           // row group 0..15
    const int cg   = blk & 15;           // col group 0..15

    int r = rg * 4 + wrow; if (r > 60) r = 60;   // clamp (dup work, writes guarded)
    const int c0 = cg * 4;
    const int rbase = r * 49152;          // *16*1024*3

    float acc[4][KCLS];
#pragma unroll
    for (int p = 0; p < 4; ++p)
#pragma unroll
        for (int k = 0; k < KCLS; ++k) acc[p][k] = 0.0f;

    int coff[4];
#pragma unroll
    for (int p = 0; p < 4; ++p) {
        int c = c0 + p; if (c > 60) c = 60;
        coff[p] = c * 48;                 // *16*3 floats (multiple of 4)
    }

    for (int chunk = 0; chunk < 6; ++chunk) {
        __syncthreads();                  // previous chunk's LDS reads done
        // stage W[chunk*2048 .. +2048) transposed into LDS (coalesced global)
        for (int f = tid; f < 20480; f += 1024) {
            const int ff = chunk * 20480 + f;
            const int d  = ff / 10;
            const int kk = ff - d * 10;
            wlds[kk * WPAD + (d - (chunk << 11))] = W[ff];
        }
        __syncthreads();

#pragma unroll
        for (int it = 0; it < 2; ++it) {
            const int dloc = (it << 10) + (tsub << 2);     // 0..2044, step 4
            const int d    = (chunk << 11) + dloc;
            const int i    = d / 192;                      // row within patch
            const int rem  = d - i * 192;                  // rem+3 < 192 always
            const float* xp = x + rbase + i * 3072 + rem;
            const float4 xv0 = *(const float4*)(xp + coff[0]);
            const float4 xv1 = *(const float4*)(xp + coff[1]);
            const float4 xv2 = *(const float4*)(xp + coff[2]);
            const float4 xv3 = *(const float4*)(xp + coff[3]);
            const float* wb = wlds + dloc;
#pragma unroll
            for (int k = 0; k < KCLS; ++k) {
                const float4 wv = *(const float4*)(wb + k * WPAD);
                acc[0][k] += xv0.x*wv.x + xv0.y*wv.y + xv0.z*wv.z + xv0.w*wv.w;
                acc[1][k] += xv1.x*wv.x + xv1.y*wv.y + xv1.z*wv.z + xv1.w*wv.w;
                acc[2][k] += xv2.x*wv.x + xv2.y*wv.y + xv2.z*wv.z + xv2.w*wv.w;
                acc[3][k] += xv3.x*wv.x + xv3.y*wv.y + xv3.z*wv.z + xv3.w*wv.w;
            }
        }
    }

    // 64-lane wave reduction
#pragma unroll
    for (int p = 0; p < 4; ++p)
#pragma unroll
        for (int k = 0; k < KCLS; ++k) {
            float v = acc[p][k];
#pragma unroll
            for (int off = 32; off > 0; off >>= 1) v += __shfl_down(v, off);
            acc[p][k] = v;
        }

    const int wgrp = (tsub >> 6);
    if ((tsub & 63) == 0) {
#pragma unroll
        for (int p = 0; p < 4; ++p)
#pragma unroll
            for (int k = 0; k < KCLS; ++k) red[wrow][wgrp][p][k] = acc[p][k];
    }
    __syncthreads();

    if (tid < 16) {
        const int wr = tid >> 2;          // patch-row
        const int p  = tid & 3;           // patch-col
        const int rr = rg * 4 + wr;
        const int cc = c0 + p;
        if (rr <= 60 && cc <= 60) {
            double l[KCLS];
#pragma unroll
            for (int k = 0; k < KCLS; ++k)
                l[k] = (double)red[wr][0][p][k] + (double)red[wr][1][p][k]
                     + (double)red[wr][2][p][k] + (double)red[wr][3][p][k]
                     + (double)b[k];
            double m = l[0];
#pragma unroll
            for (int k = 1; k < KCLS; ++k) m = fmax(m, l[k]);
            double e[KCLS], s = 0.0;
#pragma unroll
            for (int k = 0; k < KCLS; ++k) { e[k] = exp(l[k] - m); s += e[k]; }
            const double inv = 1.0 / s;
            float* po = out + OUT_PROB + (size_t)(rr * 61 + cc) * KCLS;
#pragma unroll
            for (int k = 0; k < KCLS; ++k) po[k] = (float)(e[k] * inv);
        }
    }
}

// ---------------- Stage 2+3: union-find CC + boxes (one block/class) -------
// Reference: 244-step Jacobi min-propagation -> fixed point = per-component
// min initial label (= min linear idx + 1). Union-find by min index computes
// exactly that root, bit-identical labels, with 3 barriers instead of ~300.
__device__ __forceinline__ int uf_find(int* par, int xx) {
    int x = xx;
    while (true) {
        const int p = ((volatile int*)par)[x];
        if (p == x) return x;
        const int gp = ((volatile int*)par)[p];
        if (gp == p) return p;
        atomicCAS(&par[x], p, gp);   // path-halving; monotone-decreasing invariant
        x = gp;
    }
}

__device__ __forceinline__ void uf_union(int* par, int a, int b) {
    int ra = uf_find(par, a);
    int rb = uf_find(par, b);
    while (ra != rb) {
        if (ra < rb) { const int t = ra; ra = rb; rb = t; }   // ra > rb
        const int old = atomicMin(&par[ra], rb);
        if (old == ra || old == rb) break;
        const int hi = old > rb ? old : rb;
        const int lo = old ^ rb ^ hi;
        ra = uf_find(par, hi);
        rb = uf_find(par, lo);
    }
}

__global__ __launch_bounds__(1024) void k2_cc_boxes(float* __restrict__ out)
{
    const int k   = blockIdx.x;
    const int tid = threadIdx.x;

    __shared__ int par[NCELL];
    __shared__ int rmn[NCELL + 1], rmx[NCELL + 1], cmn[NCELL + 1], cmx[NCELL + 1];

    for (int s = tid; s <= NCELL; s += 1024) {
        rmn[s] = 0x7fffffff; cmn[s] = 0x7fffffff; rmx[s] = -1; cmx[s] = -1;
    }
    // init parents from mask
    for (int idx = tid; idx < NCELL; idx += 1024) {
        const float pv = out[OUT_PROB + (size_t)idx * KCLS + k];
        par[idx] = (pv > 0.7f) ? idx : -1;
    }
    __syncthreads();

    // union with left/up neighbors (2 edges/cell cover 4-connectivity)
    for (int idx = tid; idx < NCELL; idx += 1024) {
        if (par[idx] < 0) continue;
        const int r = idx / 61, c = idx - r * 61;
        if (c > 0 && par[idx - 1]  >= 0) uf_union(par, idx, idx - 1);
        if (r > 0 && par[idx - 61] >= 0) uf_union(par, idx, idx - 61);
    }
    __syncthreads();

    // labels + box accumulation
    for (int idx = tid; idx < NCELL; idx += 1024) {
        int lab = 0;
        if (par[idx] >= 0) {
            const int root = uf_find(par, idx);
            lab = root + 1;
            const int r = idx / 61, c = idx - r * 61;
            atomicMin(&rmn[lab], r); atomicMax(&rmx[lab], r);
            atomicMin(&cmn[lab], c); atomicMax(&cmx[lab], c);
        }
        out[OUT_LAB + (size_t)idx * KCLS + k] = (float)lab;
    }
    __syncthreads();

    // boxes + valid (every slot written every launch: d_out is re-poisoned)
    for (int s = tid; s <= NCELL; s += 1024) {
        const bool val = (s > 0) && (rmx[s] >= 0);
        float* bo = out + OUT_BOX + (size_t)(k * (NCELL + 1) + s) * 4;
        if (val) {
            bo[0] = (float)(rmn[s] - 1);
            bo[1] = (float)(cmn[s] - 1);
            bo[2] = (float)(rmx[s] + 1);
            bo[3] = (float)(cmx[s] + 1);
        } else {
            bo[0] = 0.0f; bo[1] = 0.0f; bo[2] = 0.0f; bo[3] = 0.0f;
        }
        out[OUT_VALID + (size_t)k * (NCELL + 1) + s] = val ? 1.0f : 0.0f;
    }
}

extern "C" void kernel_launch(void* const* d_in, const int* in_sizes, int n_in,
                              void* d_out, int out_size, void* d_ws, size_t ws_size,
                              hipStream_t stream) {
    const float* x = (const float*)d_in[0];   // (1,1024,1024,3) f32
    const float* W = (const float*)d_in[1];   // (12288,10) f32
    const float* b = (const float*)d_in[2];   // (10,) f32
    float* out = (float*)d_out;

    k1_logits  <<<dim3(256), dim3(1024), 0, stream>>>(x, W, b, out);
    k2_cc_boxes<<<dim3(KCLS), dim3(1024), 0, stream>>>(out);
}

// Round 6
// 164.260 us; speedup vs baseline: 1.0261x; 1.0261x over previous
//
#include <hip/hip_runtime.h>
#include <cmath>

#define NCELL 3721          // 61*61
#define KCLS 10
#define DDIM 12288          // 64*64*3
#define WPAD 2052           // LDS plane stride in floats (2052*4 B = 16B-aligned)

// d_out layout (all float32), concatenated in reference return order
#define OUT_PROB 0
#define OUT_LAB  37210
#define OUT_BOX  74420
#define OUT_VALID 223300

// ---------------- Stage 1: patch GEMM (+bias) + softmax ----------------
// 256 blocks x 1024 threads, 1 block/CU. __launch_bounds__(1024,4):
// 4 waves/EU -> VGPR cap 128 (NOT the default 64 that spilled in R5:
// WRITE_SIZE 175 MB of scratch traffic). Inner-loop live set ~80 VGPRs
// (acc[4][10] + 4x float4 + addressing) fits under 128.
__global__ __launch_bounds__(1024, 4) void k1_logits(
    const float* __restrict__ x, const float* __restrict__ W,
    const float* __restrict__ b, float* __restrict__ out)
{
    __shared__ float wlds[KCLS * WPAD];          // 82,080 B
    __shared__ float red[4][4][4][KCLS];         //  2,560 B

    const int tid  = threadIdx.x;
    const int tsub = tid & 255;          // d-lane within row group
    const int wrow = tid >> 8;           // patch-row within block (0..3)
    const int blk  = blockIdx.x;
    const int rg   = blk >> 4;           // row group 0..15
    const int cg   = blk & 15;           // col group 0..15

    int r = rg * 4 + wrow; if (r > 60) r = 60;   // clamp (dup work, writes guarded)
    const int c0 = cg * 4;
    const int rbase = r * 49152;          // *16*1024*3

    float acc[4][KCLS];
#pragma unroll
    for (int p = 0; p < 4; ++p)
#pragma unroll
        for (int k = 0; k < KCLS; ++k) acc[p][k] = 0.0f;

    int coff[4];
#pragma unroll
    for (int p = 0; p < 4; ++p) {
        int c = c0 + p; if (c > 60) c = 60;
        coff[p] = c * 48;                 // *16*3 floats (multiple of 4)
    }

    for (int chunk = 0; chunk < 6; ++chunk) {
        __syncthreads();                  // previous chunk's LDS reads done
        // stage W[chunk*2048 .. +2048) transposed into LDS (coalesced global)
        for (int f = tid; f < 20480; f += 1024) {
            const int ff = chunk * 20480 + f;
            const int d  = ff / 10;
            const int kk = ff - d * 10;
            wlds[kk * WPAD + (d - (chunk << 11))] = W[ff];
        }
        __syncthreads();

#pragma unroll
        for (int it = 0; it < 2; ++it) {
            const int dloc = (it << 10) + (tsub << 2);     // 0..2044, step 4
            const int d    = (chunk << 11) + dloc;
            const int i    = d / 192;                      // row within patch
            const int rem  = d - i * 192;                  // rem+3 < 192 always
            const float* xp = x + rbase + i * 3072 + rem;
            const float4 xv0 = *(const float4*)(xp + coff[0]);
            const float4 xv1 = *(const float4*)(xp + coff[1]);
            const float4 xv2 = *(const float4*)(xp + coff[2]);
            const float4 xv3 = *(const float4*)(xp + coff[3]);
            const float* wb = wlds + dloc;
#pragma unroll
            for (int k = 0; k < KCLS; ++k) {
                const float4 wv = *(const float4*)(wb + k * WPAD);
                acc[0][k] += xv0.x*wv.x + xv0.y*wv.y + xv0.z*wv.z + xv0.w*wv.w;
                acc[1][k] += xv1.x*wv.x + xv1.y*wv.y + xv1.z*wv.z + xv1.w*wv.w;
                acc[2][k] += xv2.x*wv.x + xv2.y*wv.y + xv2.z*wv.z + xv2.w*wv.w;
                acc[3][k] += xv3.x*wv.x + xv3.y*wv.y + xv3.z*wv.z + xv3.w*wv.w;
            }
        }
    }

    // 64-lane wave reduction
#pragma unroll
    for (int p = 0; p < 4; ++p)
#pragma unroll
        for (int k = 0; k < KCLS; ++k) {
            float v = acc[p][k];
#pragma unroll
            for (int off = 32; off > 0; off >>= 1) v += __shfl_down(v, off);
            acc[p][k] = v;
        }

    const int wgrp = (tsub >> 6);
    if ((tsub & 63) == 0) {
#pragma unroll
        for (int p = 0; p < 4; ++p)
#pragma unroll
            for (int k = 0; k < KCLS; ++k) red[wrow][wgrp][p][k] = acc[p][k];
    }
    __syncthreads();

    if (tid < 16) {
        const int wr = tid >> 2;          // patch-row
        const int p  = tid & 3;           // patch-col
        const int rr = rg * 4 + wr;
        const int cc = c0 + p;
        if (rr <= 60 && cc <= 60) {
            double l[KCLS];
#pragma unroll
            for (int k = 0; k < KCLS; ++k)
                l[k] = (double)red[wr][0][p][k] + (double)red[wr][1][p][k]
                     + (double)red[wr][2][p][k] + (double)red[wr][3][p][k]
                     + (double)b[k];
            double m = l[0];
#pragma unroll
            for (int k = 1; k < KCLS; ++k) m = fmax(m, l[k]);
            double e[KCLS], s = 0.0;
#pragma unroll
            for (int k = 0; k < KCLS; ++k) { e[k] = exp(l[k] - m); s += e[k]; }
            const double inv = 1.0 / s;
            float* po = out + OUT_PROB + (size_t)(rr * 61 + cc) * KCLS;
#pragma unroll
            for (int k = 0; k < KCLS; ++k) po[k] = (float)(e[k] * inv);
        }
    }
}

// ---------------- Stage 2+3: union-find CC + boxes (one block/class) -------
// Reference: 244-step Jacobi min-propagation -> fixed point = per-component
// min initial label (= min linear idx + 1). Union-find by min index computes
// exactly that root, bit-identical labels, with 3 barriers instead of ~300.
__device__ __forceinline__ int uf_find(int* par, int xx) {
    int x = xx;
    while (true) {
        const int p = ((volatile int*)par)[x];
        if (p == x) return x;
        const int gp = ((volatile int*)par)[p];
        if (gp == p) return p;
        atomicCAS(&par[x], p, gp);   // path-halving; monotone-decreasing invariant
        x = gp;
    }
}

__device__ __forceinline__ void uf_union(int* par, int a, int b) {
    int ra = uf_find(par, a);
    int rb = uf_find(par, b);
    while (ra != rb) {
        if (ra < rb) { const int t = ra; ra = rb; rb = t; }   // ra > rb
        const int old = atomicMin(&par[ra], rb);
        if (old == ra || old == rb) break;
        const int hi = old > rb ? old : rb;
        const int lo = old ^ rb ^ hi;
        ra = uf_find(par, hi);
        rb = uf_find(par, lo);
    }
}

__global__ __launch_bounds__(1024) void k2_cc_boxes(float* __restrict__ out)
{
    const int k   = blockIdx.x;
    const int tid = threadIdx.x;

    __shared__ int par[NCELL];
    __shared__ int rmn[NCELL + 1], rmx[NCELL + 1], cmn[NCELL + 1], cmx[NCELL + 1];

    for (int s = tid; s <= NCELL; s += 1024) {
        rmn[s] = 0x7fffffff; cmn[s] = 0x7fffffff; rmx[s] = -1; cmx[s] = -1;
    }
    // init parents from mask
    for (int idx = tid; idx < NCELL; idx += 1024) {
        const float pv = out[OUT_PROB + (size_t)idx * KCLS + k];
        par[idx] = (pv > 0.7f) ? idx : -1;
    }
    __syncthreads();

    // union with left/up neighbors (2 edges/cell cover 4-connectivity)
    for (int idx = tid; idx < NCELL; idx += 1024) {
        if (par[idx] < 0) continue;
        const int r = idx / 61, c = idx - r * 61;
        if (c > 0 && par[idx - 1]  >= 0) uf_union(par, idx, idx - 1);
        if (r > 0 && par[idx - 61] >= 0) uf_union(par, idx, idx - 61);
    }
    __syncthreads();

    // labels + box accumulation
    for (int idx = tid; idx < NCELL; idx += 1024) {
        int lab = 0;
        if (par[idx] >= 0) {
            const int root = uf_find(par, idx);
            lab = root + 1;
            const int r = idx / 61, c = idx - r * 61;
            atomicMin(&rmn[lab], r); atomicMax(&rmx[lab], r);
            atomicMin(&cmn[lab], c); atomicMax(&cmx[lab], c);
        }
        out[OUT_LAB + (size_t)idx * KCLS + k] = (float)lab;
    }
    __syncthreads();

    // boxes + valid (every slot written every launch: d_out is re-poisoned)
    for (int s = tid; s <= NCELL; s += 1024) {
        const bool val = (s > 0) && (rmx[s] >= 0);
        float* bo = out + OUT_BOX + (size_t)(k * (NCELL + 1) + s) * 4;
        if (val) {
            bo[0] = (float)(rmn[s] - 1);
            bo[1] = (float)(cmn[s] - 1);
            bo[2] = (float)(rmx[s] + 1);
            bo[3] = (float)(cmx[s] + 1);
        } else {
            bo[0] = 0.0f; bo[1] = 0.0f; bo[2] = 0.0f; bo[3] = 0.0f;
        }
        out[OUT_VALID + (size_t)k * (NCELL + 1) + s] = val ? 1.0f : 0.0f;
    }
}

extern "C" void kernel_launch(void* const* d_in, const int* in_sizes, int n_in,
                              void* d_out, int out_size, void* d_ws, size_t ws_size,
                              hipStream_t stream) {
    const float* x = (const float*)d_in[0];   // (1,1024,1024,3) f32
    const float* W = (const float*)d_in[1];   // (12288,10) f32
    const float* b = (const float*)d_in[2];   // (10,) f32
    float* out = (float*)d_out;

    k1_logits  <<<dim3(256), dim3(1024), 0, stream>>>(x, W, b, out);
    k2_cc_boxes<<<dim3(KCLS), dim3(1024), 0, stream>>>(out);
}

// Round 7
// 117.895 us; speedup vs baseline: 1.4296x; 1.3933x over previous
//
#include <hip/hip_runtime.h>
#include <cmath>

#define NCELL 3721          // 61*61
#define KCLS 10
#define DDIM 12288          // 64*64*3
#define WPAD 2052           // LDS plane stride in floats (2052*4 B = 16B-aligned)

// d_out layout (all float32), concatenated in reference return order
#define OUT_PROB 0
#define OUT_LAB  37210
#define OUT_BOX  74420
#define OUT_VALID 223300

// ---------------- Stage 1: patch GEMM (+bias) + softmax ----------------
// 256 blocks x 1024 threads, 1 block/CU (85 KB LDS). amdgpu_waves_per_eu(4,4)
// pins the RA occupancy target at 4 waves/EU -> 128-VGPR budget (R5/R6: the
// default 8-wave target capped at 64 VGPRs and spilled 300 MB of scratch).
// Additionally the live set is kept < 64 regs (acc[4][10]=40 + 4x float2 xv
// + float2 wv + addressing, it-loop NOT unrolled) so no spill even if the
// attribute is ignored.
__global__ __launch_bounds__(1024)
__attribute__((amdgpu_waves_per_eu(4, 4)))
void k1_logits(
    const float* __restrict__ x, const float* __restrict__ W,
    const float* __restrict__ b, float* __restrict__ out)
{
    __shared__ float wlds[KCLS * WPAD];          // 82,080 B
    __shared__ float red[4][4][4][KCLS];         //  2,560 B

    const int tid  = threadIdx.x;
    const int tsub = tid & 255;          // d-lane within row group
    const int wrow = tid >> 8;           // patch-row within block (0..3)
    const int blk  = blockIdx.x;
    const int rg   = blk >> 4;           // row group 0..15
    const int cg   = blk & 15;           // col group 0..15

    int r = rg * 4 + wrow; if (r > 60) r = 60;   // clamp (dup work, writes guarded)
    const int c0 = cg * 4;
    const int rbase = r * 49152;          // *16*1024*3

    float acc[4][KCLS];
#pragma unroll
    for (int p = 0; p < 4; ++p)
#pragma unroll
        for (int k = 0; k < KCLS; ++k) acc[p][k] = 0.0f;

    int coff[4];
#pragma unroll
    for (int p = 0; p < 4; ++p) {
        int c = c0 + p; if (c > 60) c = 60;
        coff[p] = c * 48;                 // *16*3 floats
    }

    for (int chunk = 0; chunk < 6; ++chunk) {
        __syncthreads();                  // previous chunk's LDS reads done
        // stage W[chunk*2048 .. +2048) transposed into LDS (coalesced global)
        for (int f = tid; f < 20480; f += 1024) {
            const int ff = chunk * 20480 + f;
            const int d  = ff / 10;
            const int kk = ff - d * 10;
            wlds[kk * WPAD + (d - (chunk << 11))] = W[ff];
        }
        __syncthreads();

#pragma unroll 1
        for (int it = 0; it < 4; ++it) {
            const int dloc = (it << 9) + (tsub << 1);      // 0..2046, step 2
            const int d    = (chunk << 11) + dloc;
            const int i    = d / 192;                      // row within patch
            const int rem  = d - i * 192;                  // rem+1 < 192 (rem even)
            const float* xp = x + rbase + i * 3072 + rem;
            const float2 xv0 = *(const float2*)(xp + coff[0]);
            const float2 xv1 = *(const float2*)(xp + coff[1]);
            const float2 xv2 = *(const float2*)(xp + coff[2]);
            const float2 xv3 = *(const float2*)(xp + coff[3]);
            const float* wb = wlds + dloc;
#pragma unroll
            for (int k = 0; k < KCLS; ++k) {
                const float2 wv = *(const float2*)(wb + k * WPAD);
                acc[0][k] += xv0.x*wv.x + xv0.y*wv.y;
                acc[1][k] += xv1.x*wv.x + xv1.y*wv.y;
                acc[2][k] += xv2.x*wv.x + xv2.y*wv.y;
                acc[3][k] += xv3.x*wv.x + xv3.y*wv.y;
            }
        }
    }

    // 64-lane wave reduction
#pragma unroll
    for (int p = 0; p < 4; ++p)
#pragma unroll
        for (int k = 0; k < KCLS; ++k) {
            float v = acc[p][k];
#pragma unroll
            for (int off = 32; off > 0; off >>= 1) v += __shfl_down(v, off);
            acc[p][k] = v;
        }

    const int wgrp = (tsub >> 6);
    if ((tsub & 63) == 0) {
#pragma unroll
        for (int p = 0; p < 4; ++p)
#pragma unroll
            for (int k = 0; k < KCLS; ++k) red[wrow][wgrp][p][k] = acc[p][k];
    }
    __syncthreads();

    if (tid < 16) {
        const int wr = tid >> 2;          // patch-row
        const int p  = tid & 3;           // patch-col
        const int rr = rg * 4 + wr;
        const int cc = c0 + p;
        if (rr <= 60 && cc <= 60) {
            double l[KCLS];
#pragma unroll
            for (int k = 0; k < KCLS; ++k)
                l[k] = (double)red[wr][0][p][k] + (double)red[wr][1][p][k]
                     + (double)red[wr][2][p][k] + (double)red[wr][3][p][k]
                     + (double)b[k];
            double m = l[0];
#pragma unroll
            for (int k = 1; k < KCLS; ++k) m = fmax(m, l[k]);
            double e[KCLS], s = 0.0;
#pragma unroll
            for (int k = 0; k < KCLS; ++k) { e[k] = exp(l[k] - m); s += e[k]; }
            const double inv = 1.0 / s;
            float* po = out + OUT_PROB + (size_t)(rr * 61 + cc) * KCLS;
#pragma unroll
            for (int k = 0; k < KCLS; ++k) po[k] = (float)(e[k] * inv);
        }
    }
}

// ---------------- Stage 2+3: union-find CC + boxes (one block/class) -------
// Reference: 244-step Jacobi min-propagation -> fixed point = per-component
// min initial label (= min linear idx + 1). Union-find by min index computes
// exactly that root, bit-identical labels, with 3 barriers instead of ~300.
__device__ __forceinline__ int uf_find(int* par, int xx) {
    int x = xx;
    while (true) {
        const int p = ((volatile int*)par)[x];
        if (p == x) return x;
        const int gp = ((volatile int*)par)[p];
        if (gp == p) return p;
        atomicCAS(&par[x], p, gp);   // path-halving; monotone-decreasing invariant
        x = gp;
    }
}

__device__ __forceinline__ void uf_union(int* par, int a, int b) {
    int ra = uf_find(par, a);
    int rb = uf_find(par, b);
    while (ra != rb) {
        if (ra < rb) { const int t = ra; ra = rb; rb = t; }   // ra > rb
        const int old = atomicMin(&par[ra], rb);
        if (old == ra || old == rb) break;
        const int hi = old > rb ? old : rb;
        const int lo = old ^ rb ^ hi;
        ra = uf_find(par, hi);
        rb = uf_find(par, lo);
    }
}

__global__ __launch_bounds__(1024) void k2_cc_boxes(float* __restrict__ out)
{
    const int k   = blockIdx.x;
    const int tid = threadIdx.x;

    __shared__ int par[NCELL];
    __shared__ int rmn[NCELL + 1], rmx[NCELL + 1], cmn[NCELL + 1], cmx[NCELL + 1];

    for (int s = tid; s <= NCELL; s += 1024) {
        rmn[s] = 0x7fffffff; cmn[s] = 0x7fffffff; rmx[s] = -1; cmx[s] = -1;
    }
    // init parents from mask
    for (int idx = tid; idx < NCELL; idx += 1024) {
        const float pv = out[OUT_PROB + (size_t)idx * KCLS + k];
        par[idx] = (pv > 0.7f) ? idx : -1;
    }
    __syncthreads();

    // union with left/up neighbors (2 edges/cell cover 4-connectivity)
    for (int idx = tid; idx < NCELL; idx += 1024) {
        if (par[idx] < 0) continue;
        const int r = idx / 61, c = idx - r * 61;
        if (c > 0 && par[idx - 1]  >= 0) uf_union(par, idx, idx - 1);
        if (r > 0 && par[idx - 61] >= 0) uf_union(par, idx, idx - 61);
    }
    __syncthreads();

    // labels + box accumulation
    for (int idx = tid; idx < NCELL; idx += 1024) {
        int lab = 0;
        if (par[idx] >= 0) {
            const int root = uf_find(par, idx);
            lab = root + 1;
            const int r = idx / 61, c = idx - r * 61;
            atomicMin(&rmn[lab], r); atomicMax(&rmx[lab], r);
            atomicMin(&cmn[lab], c); atomicMax(&cmx[lab], c);
        }
        out[OUT_LAB + (size_t)idx * KCLS + k] = (float)lab;
    }
    __syncthreads();

    // boxes + valid (every slot written every launch: d_out is re-poisoned)
    for (int s = tid; s <= NCELL; s += 1024) {
        const bool val = (s > 0) && (rmx[s] >= 0);
        float* bo = out + OUT_BOX + (size_t)(k * (NCELL + 1) + s) * 4;
        if (val) {
            bo[0] = (float)(rmn[s] - 1);
            bo[1] = (float)(cmn[s] - 1);
            bo[2] = (float)(rmx[s] + 1);
            bo[3] = (float)(cmx[s] + 1);
        } else {
            bo[0] = 0.0f; bo[1] = 0.0f; bo[2] = 0.0f; bo[3] = 0.0f;
        }
        out[OUT_VALID + (size_t)k * (NCELL + 1) + s] = val ? 1.0f : 0.0f;
    }
}

extern "C" void kernel_launch(void* const* d_in, const int* in_sizes, int n_in,
                              void* d_out, int out_size, void* d_ws, size_t ws_size,
                              hipStream_t stream) {
    const float* x = (const float*)d_in[0];   // (1,1024,1024,3) f32
    const float* W = (const float*)d_in[1];   // (12288,10) f32
    const float* b = (const float*)d_in[2];   // (10,) f32
    float* out = (float*)d_out;

    k1_logits  <<<dim3(256), dim3(1024), 0, stream>>>(x, W, b, out);
    k2_cc_boxes<<<dim3(KCLS), dim3(1024), 0, stream>>>(out);
}

// Round 10
// 116.971 us; speedup vs baseline: 1.4409x; 1.0079x over previous
//
#include <hip/hip_runtime.h>
#include <cmath>

#define NCELL 3721          // 61*61
#define KCLS 10
#define DDIM 12288          // 64*64*3
#define WPAD 2052           // LDS plane stride in floats (2052*4 B = 16B-aligned)

// d_out layout (all float32), concatenated in reference return order
#define OUT_PROB 0
#define OUT_LAB  37210
#define OUT_BOX  74420
#define OUT_VALID 223300

// ---------------- Stage 1: patch GEMM (+bias) + softmax ----------------
// 256 blocks x 1024 threads, 1 block/CU (85 KB LDS -> 4 waves/EU max).
// amdgpu_waves_per_eu(4,4) pins the RA target at 4 waves/EU -> 128-VGPR
// budget (proven safe in R7 at VGPR=52). Body: R7's float2 loop with
// unroll 2 — two iterations' loads (8 global_load_dwordx2 + 20 ds_read_b64)
// overlap 160 FMAs. Live set ~70 regs, inside budget, no spill expected.
// NOTE: float4 body + this attribute killed the container in R8/R9 (4x) —
// suspected toolchain pathology on the bigger unrolled block; do not revisit.
// Spill canary: WRITE_SIZE must stay ~168 KB (R5 spilled 175 MB).
__global__ __launch_bounds__(1024)
__attribute__((amdgpu_waves_per_eu(4, 4)))
void k1_logits(
    const float* __restrict__ x, const float* __restrict__ W,
    const float* __restrict__ b, float* __restrict__ out)
{
    __shared__ float wlds[KCLS * WPAD];          // 82,080 B
    __shared__ float red[4][4][4][KCLS];         //  2,560 B

    const int tid  = threadIdx.x;
    const int tsub = tid & 255;          // d-lane within row group
    const int wrow = tid >> 8;           // patch-row within block (0..3)
    const int blk  = blockIdx.x;
    const int rg   = blk >> 4;           // row group 0..15
    const int cg   = blk & 15;           // col group 0..15

    int r = rg * 4 + wrow; if (r > 60) r = 60;   // clamp (dup work, writes guarded)
    const int c0 = cg * 4;
    const int rbase = r * 49152;          // *16*1024*3

    float acc[4][KCLS];
#pragma unroll
    for (int p = 0; p < 4; ++p)
#pragma unroll
        for (int k = 0; k < KCLS; ++k) acc[p][k] = 0.0f;

    int coff[4];
#pragma unroll
    for (int p = 0; p < 4; ++p) {
        int c = c0 + p; if (c > 60) c = 60;
        coff[p] = c * 48;                 // *16*3 floats
    }

    for (int chunk = 0; chunk < 6; ++chunk) {
        __syncthreads();                  // previous chunk's LDS reads done
        // stage W[chunk*2048 .. +2048) transposed into LDS (coalesced global)
        for (int f = tid; f < 20480; f += 1024) {
            const int ff = chunk * 20480 + f;
            const int d  = ff / 10;
            const int kk = ff - d * 10;
            wlds[kk * WPAD + (d - (chunk << 11))] = W[ff];
        }
        __syncthreads();

#pragma unroll 2
        for (int it = 0; it < 4; ++it) {
            const int dloc = (it << 9) + (tsub << 1);      // 0..2046, step 2
            const int d    = (chunk << 11) + dloc;
            const int i    = d / 192;                      // row within patch
            const int rem  = d - i * 192;                  // rem+1 < 192 (rem even)
            const float* xp = x + rbase + i * 3072 + rem;
            const float2 xv0 = *(const float2*)(xp + coff[0]);
            const float2 xv1 = *(const float2*)(xp + coff[1]);
            const float2 xv2 = *(const float2*)(xp + coff[2]);
            const float2 xv3 = *(const float2*)(xp + coff[3]);
            const float* wb = wlds + dloc;
#pragma unroll
            for (int k = 0; k < KCLS; ++k) {
                const float2 wv = *(const float2*)(wb + k * WPAD);
                acc[0][k] += xv0.x*wv.x + xv0.y*wv.y;
                acc[1][k] += xv1.x*wv.x + xv1.y*wv.y;
                acc[2][k] += xv2.x*wv.x + xv2.y*wv.y;
                acc[3][k] += xv3.x*wv.x + xv3.y*wv.y;
            }
        }
    }

    // 64-lane wave reduction
#pragma unroll
    for (int p = 0; p < 4; ++p)
#pragma unroll
        for (int k = 0; k < KCLS; ++k) {
            float v = acc[p][k];
#pragma unroll
            for (int off = 32; off > 0; off >>= 1) v += __shfl_down(v, off);
            acc[p][k] = v;
        }

    const int wgrp = (tsub >> 6);
    if ((tsub & 63) == 0) {
#pragma unroll
        for (int p = 0; p < 4; ++p)
#pragma unroll
            for (int k = 0; k < KCLS; ++k) red[wrow][wgrp][p][k] = acc[p][k];
    }
    __syncthreads();

    if (tid < 16) {
        const int wr = tid >> 2;          // patch-row
        const int p  = tid & 3;           // patch-col
        const int rr = rg * 4 + wr;
        const int cc = c0 + p;
        if (rr <= 60 && cc <= 60) {
            double l[KCLS];
#pragma unroll
            for (int k = 0; k < KCLS; ++k)
                l[k] = (double)red[wr][0][p][k] + (double)red[wr][1][p][k]
                     + (double)red[wr][2][p][k] + (double)red[wr][3][p][k]
                     + (double)b[k];
            double m = l[0];
#pragma unroll
            for (int k = 1; k < KCLS; ++k) m = fmax(m, l[k]);
            double e[KCLS], s = 0.0;
#pragma unroll
            for (int k = 0; k < KCLS; ++k) { e[k] = exp(l[k] - m); s += e[k]; }
            const double inv = 1.0 / s;
            float* po = out + OUT_PROB + (size_t)(rr * 61 + cc) * KCLS;
#pragma unroll
            for (int k = 0; k < KCLS; ++k) po[k] = (float)(e[k] * inv);
        }
    }
}

// ---------------- Stage 2+3: union-find CC + boxes (one block/class) -------
// Reference: 244-step Jacobi min-propagation -> fixed point = per-component
// min initial label (= min linear idx + 1). Union-find by min index computes
// exactly that root, bit-identical labels, with 3 barriers instead of ~300.
__device__ __forceinline__ int uf_find(int* par, int xx) {
    int x = xx;
    while (true) {
        const int p = ((volatile int*)par)[x];
        if (p == x) return x;
        const int gp = ((volatile int*)par)[p];
        if (gp == p) return p;
        atomicCAS(&par[x], p, gp);   // path-halving; monotone-decreasing invariant
        x = gp;
    }
}

__device__ __forceinline__ void uf_union(int* par, int a, int b) {
    int ra = uf_find(par, a);
    int rb = uf_find(par, b);
    while (ra != rb) {
        if (ra < rb) { const int t = ra; ra = rb; rb = t; }   // ra > rb
        const int old = atomicMin(&par[ra], rb);
        if (old == ra || old == rb) break;
        const int hi = old > rb ? old : rb;
        const int lo = old ^ rb ^ hi;
        ra = uf_find(par, hi);
        rb = uf_find(par, lo);
    }
}

__global__ __launch_bounds__(1024) void k2_cc_boxes(float* __restrict__ out)
{
    const int k   = blockIdx.x;
    const int tid = threadIdx.x;

    __shared__ int par[NCELL];
    __shared__ int rmn[NCELL + 1], rmx[NCELL + 1], cmn[NCELL + 1], cmx[NCELL + 1];

    for (int s = tid; s <= NCELL; s += 1024) {
        rmn[s] = 0x7fffffff; cmn[s] = 0x7fffffff; rmx[s] = -1; cmx[s] = -1;
    }
    // init parents from mask
    for (int idx = tid; idx < NCELL; idx += 1024) {
        const float pv = out[OUT_PROB + (size_t)idx * KCLS + k];
        par[idx] = (pv > 0.7f) ? idx : -1;
    }
    __syncthreads();

    // union with left/up neighbors (2 edges/cell cover 4-connectivity)
    for (int idx = tid; idx < NCELL; idx += 1024) {
        if (par[idx] < 0) continue;
        const int r = idx / 61, c = idx - r * 61;
        if (c > 0 && par[idx - 1]  >= 0) uf_union(par, idx, idx - 1);
        if (r > 0 && par[idx - 61] >= 0) uf_union(par, idx, idx - 61);
    }
    __syncthreads();

    // labels + box accumulation
    for (int idx = tid; idx < NCELL; idx += 1024) {
        int lab = 0;
        if (par[idx] >= 0) {
            const int root = uf_find(par, idx);
            lab = root + 1;
            const int r = idx / 61, c = idx - r * 61;
            atomicMin(&rmn[lab], r); atomicMax(&rmx[lab], r);
            atomicMin(&cmn[lab], c); atomicMax(&cmx[lab], c);
        }
        out[OUT_LAB + (size_t)idx * KCLS + k] = (float)lab;
    }
    __syncthreads();

    // boxes + valid (every slot written every launch: d_out is re-poisoned)
    for (int s = tid; s <= NCELL; s += 1024) {
        const bool val = (s > 0) && (rmx[s] >= 0);
        float* bo = out + OUT_BOX + (size_t)(k * (NCELL + 1) + s) * 4;
        if (val) {
            bo[0] = (float)(rmn[s] - 1);
            bo[1] = (float)(cmn[s] - 1);
            bo[2] = (float)(rmx[s] + 1);
            bo[3] = (float)(cmx[s] + 1);
        } else {
            bo[0] = 0.0f; bo[1] = 0.0f; bo[2] = 0.0f; bo[3] = 0.0f;
        }
        out[OUT_VALID + (size_t)k * (NCELL + 1) + s] = val ? 1.0f : 0.0f;
    }
}

extern "C" void kernel_launch(void* const* d_in, const int* in_sizes, int n_in,
                              void* d_out, int out_size, void* d_ws, size_t ws_size,
                              hipStream_t stream) {
    const float* x = (const float*)d_in[0];   // (1,1024,1024,3) f32
    const float* W = (const float*)d_in[1];   // (12288,10) f32
    const float* b = (const float*)d_in[2];   // (10,) f32
    float* out = (float*)d_out;

    k1_logits  <<<dim3(256), dim3(1024), 0, stream>>>(x, W, b, out);
    k2_cc_boxes<<<dim3(KCLS), dim3(1024), 0, stream>>>(out);
}